// Round 5
// baseline (181.174 us; speedup 1.0000x reference)
//
#include <hip/hip_runtime.h>

namespace {

constexpr int NV = 512;
typedef unsigned long long ull;
constexpr ull INF64 = ~0ULL;
constexpr unsigned WMAX = 0xFFFFFFFFu;

// Edge total order = reference's stable sort: (f32 weight bits, triu index).
// triu index is order-isomorphic to lex (i,j), i<j, so the canonical key
// (w_bits<<32)|(i<<9)|j induces the identical order (w>=0 -> bits monotone).
// Keys globally unique -> unique MST -> Boruvka == Kruskal's accepted set.
__global__ __launch_bounds__(1024) void boruvka_loss(
    const float* __restrict__ d1, const float* __restrict__ d2,
    float* __restrict__ partial)
{
    const int blk = blockIdx.x;
    const float* __restrict__ Dm = blk ? d2 : d1;
    const float* __restrict__ Do = blk ? d1 : d2;
    const int tid = threadIdx.x;
    const int lane = tid & 63;

    __shared__ __align__(16) unsigned comp[NV];  // component id per vertex
    __shared__ ull best[NV];                     // per-component min out-edge key
    __shared__ unsigned parent[NV];              // hook/contract scratch
    __shared__ int doneFlag;

    if (tid < NV) { comp[tid] = tid; best[tid] = INF64; }
    if (tid == 0) doneFlag = 0;

    const int v  = tid >> 1;              // 2 threads per row
    const int c0 = (tid & 1) << 8;        // col base 0 / 256
    const float4* __restrict__ rowp4 =
        reinterpret_cast<const float4*>(Dm + ((size_t)v << 9) + c0);
    const uint4* comp4 = reinterpret_cast<const uint4*>(&comp[c0]);

    float contrib = 0.f;                  // used by wave 0 lanes only
    int accTotal = 0;                     // uniform across wave 0

    __syncthreads();

    for (int round = 0; round < 9; ++round) {
        // ================= scan: all 16 waves =================
        {
            const unsigned cv = comp[v];
            unsigned wmin = WMAX;
            int smin = 0;
#pragma unroll 8
            for (int s = 0; s < 64; ++s) {
                float4 w4 = rowp4[s];
                uint4  q4 = comp4[s];
                unsigned m0 = (q4.x != cv) ? __float_as_uint(w4.x) : WMAX;
                unsigned m1 = (q4.y != cv) ? __float_as_uint(w4.y) : WMAX;
                unsigned m2 = (q4.z != cv) ? __float_as_uint(w4.z) : WMAX;
                unsigned m3 = (q4.w != cv) ? __float_as_uint(w4.w) : WMAX;
                unsigned t = min(min(m0, m1), min(m2, m3));
                if (t < wmin) { wmin = t; smin = s; }
            }
            if (wmin != WMAX) {
                // recover the first (smallest) column achieving wmin
                float4 w4 = rowp4[smin];
                uint4  q4 = comp4[smin];
                unsigned m0 = (q4.x != cv) ? __float_as_uint(w4.x) : WMAX;
                unsigned m1 = (q4.y != cv) ? __float_as_uint(w4.y) : WMAX;
                unsigned m2 = (q4.z != cv) ? __float_as_uint(w4.z) : WMAX;
                int k = (m0 == wmin) ? 0 : (m1 == wmin) ? 1 : (m2 == wmin) ? 2 : 3;
                unsigned umin = (unsigned)(c0 + smin * 4 + k);
                unsigned uv = (unsigned)v;
                unsigned lo = (umin < uv) ? ((umin << 9) | uv) : ((uv << 9) | umin);
                atomicMin(&best[cv], ((ull)wmin << 32) | (ull)lo);
            }
        }
        __syncthreads();   // best final; comp stable

        // ================= merge: wave 0 only, barrier-free =================
        if (tid < 64) {
            // ---- hook: component t points across its best edge
#pragma unroll
            for (int k = 0; k < 8; ++k) {
                int t = lane + 64 * k;
                ull e = best[t];
                unsigned p = (unsigned)t;
                if (e != INF64) {
                    unsigned j = (unsigned)e & 511u;
                    unsigned i = ((unsigned)e >> 9) & 511u;
                    unsigned ci = comp[i], cj = comp[j];
                    p = (ci == (unsigned)t) ? cj : ci;
                }
                parent[t] = p;
            }
            __threadfence_block();

            // ---- break 2-cycles: smaller id of a mutual pair becomes root
#pragma unroll
            for (int k = 0; k < 8; ++k) {
                int t = lane + 64 * k;
                unsigned p = parent[t];
                if (p != (unsigned)t && parent[p] == (unsigned)t && (unsigned)t < p)
                    parent[t] = (unsigned)t;
            }
            __threadfence_block();

            // ---- accept edges (dedup mutual picks by key equality)
            int accRound = 0;
#pragma unroll
            for (int k = 0; k < 8; ++k) {
                int t = lane + 64 * k;
                ull e = best[t];
                bool take = false;
                unsigned i = 0, j = 0;
                if (e != INF64) {
                    j = (unsigned)e & 511u;
                    i = ((unsigned)e >> 9) & 511u;
                    unsigned ci = comp[i], cj = comp[j];
                    unsigned p = (ci == (unsigned)t) ? cj : ci;
                    take = !((best[p] == e) && (p < (unsigned)t));
                }
                if (take) {
                    float a = __uint_as_float((unsigned)(e >> 32)); // Dm[i][j]
                    float b = Do[((size_t)i << 9) + j];
                    float d = a - b;
                    contrib += d * d;
                }
                accRound += __popcll(__ballot(take));   // uniform
            }
            accTotal += accRound;
            __threadfence_block();

            // ---- pointer jumping (9 doublings; races only accelerate)
            for (int jt = 0; jt < 9; ++jt) {
#pragma unroll
                for (int k = 0; k < 8; ++k) {
                    int t = lane + 64 * k;
                    parent[t] = parent[parent[t]];
                }
                __threadfence_block();
            }

            // ---- relabel + reset best for next round + done flag
#pragma unroll
            for (int k = 0; k < 8; ++k) {
                int t = lane + 64 * k;
                comp[t] = parent[comp[t]];
                best[t] = INF64;
            }
            if (lane == 0) doneFlag = (accTotal == NV - 1) ? 1 : 0;
        }
        __syncthreads();   // merge results visible; also publishes doneFlag
        if (doneFlag) break;
    }

    // ---- wave-0 fixed-order butterfly reduce of contributions
    if (tid < 64) {
#pragma unroll
        for (int off = 32; off >= 1; off >>= 1) contrib += __shfl_xor(contrib, off);
        if (lane == 0) partial[blk] = contrib;
    }
}

__global__ void final_add(const float* __restrict__ partial, float* __restrict__ out) {
    out[0] = partial[0] + partial[1];
}

} // namespace

extern "C" void kernel_launch(void* const* d_in, const int* in_sizes, int n_in,
                              void* d_out, int out_size, void* d_ws, size_t ws_size,
                              hipStream_t stream) {
    const float* d1 = (const float*)d_in[0];
    const float* d2 = (const float*)d_in[1];
    float* out = (float*)d_out;
    float* ws = (float*)d_ws;

    boruvka_loss<<<2, 1024, 0, stream>>>(d1, d2, ws); // writes ws[0], ws[1]
    final_add<<<1, 1, 0, stream>>>(ws, out);
}

// Round 6
// 141.595 us; speedup vs baseline: 1.2795x; 1.2795x over previous
//
#include <hip/hip_runtime.h>

namespace {

constexpr int NV = 512;
constexpr unsigned WMAX = 0xFFFFFFFFu;

// Edge total order = reference's stable sort: (f32 weight bits, triu index).
// triu index is order-isomorphic to lex (i,j), i<j, so ordering by
// (w_bits, (i<<9)|j) is identical (w>=0 -> float bits order-monotone).
// Unique keys -> unique MST -> Boruvka accepts exactly Kruskal's edge set.
__global__ __launch_bounds__(1024) void boruvka_loss(
    const float* __restrict__ d1, const float* __restrict__ d2,
    float* __restrict__ partial)
{
    const int blk = blockIdx.x;
    const float* __restrict__ Dm = blk ? d2 : d1;
    const float* __restrict__ Do = blk ? d1 : d2;
    const int tid = threadIdx.x;

    __shared__ __align__(16) unsigned comp[NV];   // vertex -> component id (a root)
    __shared__ unsigned bestW[NV];                // per-component min weight bits
    __shared__ unsigned bestLo[NV];               // per-component min (i<<9)|j at bestW
    __shared__ unsigned parent[NV];               // component hook forest
    __shared__ int waveAcc[8];
    __shared__ int accTot;
    __shared__ int doneFlag;

    if (tid < NV) { comp[tid] = tid; bestW[tid] = WMAX; bestLo[tid] = WMAX; }
    if (tid == 0) { accTot = 0; doneFlag = 0; }

    const int v  = tid >> 1;               // 2 threads per row
    const int c0 = (tid & 1) << 8;         // column half: 0 / 256
    const float4* __restrict__ rowp4 =
        reinterpret_cast<const float4*>(Dm + ((size_t)v << 9) + c0);
    const uint4* comp4 = reinterpret_cast<const uint4*>(&comp[c0]);

    // round-0 exclusion (j == v) position within this thread's half
    const int sEx = ((v & 256) == c0) ? ((v & 255) >> 2) : -1;
    const int kEx = v & 3;

    float contrib = 0.f;

    __syncthreads();

    for (int round = 0; round < 9; ++round) {
        // ================= scan phase 1: per-component min WEIGHT =========
        unsigned cv;
        unsigned wmin = WMAX;
        int smin = 0;
        if (round == 0) {
            cv = (unsigned)v;              // singleton components
#pragma unroll 8
            for (int s = 0; s < 64; ++s) {
                float4 w4 = rowp4[s];
                unsigned m0 = __float_as_uint(w4.x);
                unsigned m1 = __float_as_uint(w4.y);
                unsigned m2 = __float_as_uint(w4.z);
                unsigned m3 = __float_as_uint(w4.w);
                if (s == sEx) {            // exclude the diagonal element
                    if (kEx == 0) m0 = WMAX;
                    if (kEx == 1) m1 = WMAX;
                    if (kEx == 2) m2 = WMAX;
                    if (kEx == 3) m3 = WMAX;
                }
                unsigned t = min(min(m0, m1), min(m2, m3));
                if (t < wmin) { wmin = t; smin = s; }
            }
        } else {
            cv = comp[v];
#pragma unroll 8
            for (int s = 0; s < 64; ++s) {
                float4 w4 = rowp4[s];
                uint4  q4 = comp4[s];
                unsigned m0 = (q4.x != cv) ? __float_as_uint(w4.x) : WMAX;
                unsigned m1 = (q4.y != cv) ? __float_as_uint(w4.y) : WMAX;
                unsigned m2 = (q4.z != cv) ? __float_as_uint(w4.z) : WMAX;
                unsigned m3 = (q4.w != cv) ? __float_as_uint(w4.w) : WMAX;
                unsigned t = min(min(m0, m1), min(m2, m3));
                if (t < wmin) { wmin = t; smin = s; }
            }
        }
        // test-and-test-and-set: broadcast read prunes serialized atomics
        if (wmin != WMAX && bestW[cv] > wmin) atomicMin(&bestW[cv], wmin);
        __syncthreads();

        // ================= scan phase 2: tie-break INDEX ==================
        if (wmin != WMAX && wmin == bestW[cv]) {
            float4 w4 = rowp4[smin];       // L1-hot re-read of winning group
            unsigned m0, m1, m2, m3;
            if (round == 0) {
                m0 = __float_as_uint(w4.x); m1 = __float_as_uint(w4.y);
                m2 = __float_as_uint(w4.z); m3 = __float_as_uint(w4.w);
                if (smin == sEx) {
                    if (kEx == 0) m0 = WMAX;
                    if (kEx == 1) m1 = WMAX;
                    if (kEx == 2) m2 = WMAX;
                    if (kEx == 3) m3 = WMAX;
                }
            } else {
                uint4 q4 = comp4[smin];
                m0 = (q4.x != cv) ? __float_as_uint(w4.x) : WMAX;
                m1 = (q4.y != cv) ? __float_as_uint(w4.y) : WMAX;
                m2 = (q4.z != cv) ? __float_as_uint(w4.z) : WMAX;
                m3 = (q4.w != cv) ? __float_as_uint(w4.w) : WMAX;
            }
            int k = (m0 == wmin) ? 0 : (m1 == wmin) ? 1 : (m2 == wmin) ? 2 : 3;
            unsigned umin = (unsigned)(c0 + smin * 4 + k);
            unsigned uv = (unsigned)v;
            unsigned lo = (umin < uv) ? ((umin << 9) | uv) : ((uv << 9) | umin);
            if (bestLo[cv] > lo) atomicMin(&bestLo[cv], lo);
        }
        __syncthreads();

        // ================= hook ===========================================
        unsigned hookp = 0, hw = WMAX, hlo = 0, hi_ = 0, hj_ = 0;
        if (tid < NV) {
            unsigned t = (unsigned)tid;
            hw = bestW[t];
            unsigned p = t;
            if (hw != WMAX) {
                hlo = bestLo[t];
                hi_ = hlo >> 9; hj_ = hlo & 511u;
                unsigned ci = comp[hi_], cj = comp[hj_];
                p = (ci == t) ? cj : ci;
            }
            hookp = p;
            parent[t] = p;
        }
        __syncthreads();

        // ================= break 2-cycles (race-benign) ===================
        if (tid < NV) {
            unsigned t = (unsigned)tid;
            unsigned p = parent[t];
            if (p != t && parent[p] == t && t < p) parent[t] = t;
        }
        __syncthreads();

        // ============ accept (dedup via register hookp) + relabel walk ====
        bool take = false;
        if (tid < NV) {
            unsigned t = (unsigned)tid;
            if (hw != WMAX)
                take = !((bestW[hookp] == hw) && (bestLo[hookp] == hlo) && (hookp < t));
            if (take) {
                float a = __uint_as_float(hw);            // Dm[i][j]
                float b = Do[((size_t)hi_ << 9) + hj_];
                float d = a - b;
                contrib += d * d;
            }
            unsigned long long bal = __ballot(take);
            if ((tid & 63) == 0) waveAcc[tid >> 6] = __popcll(bal);
            // relabel vertex t: walk its component label to the forest root
            unsigned r = comp[t];
            while (parent[r] != r) r = parent[r];
            comp[t] = r;
        }
        __syncthreads();

        // ================= reset + termination ============================
        if (tid < NV) { bestW[tid] = WMAX; bestLo[tid] = WMAX; }
        if (tid == 0) {
            int s = 0;
#pragma unroll
            for (int w = 0; w < 8; ++w) s += waveAcc[w];
            accTot += s;
            doneFlag = (accTot == NV - 1) ? 1 : 0;
        }
        __syncthreads();
        if (doneFlag) break;
    }

    // ---- deterministic reduction: wave butterfly, then fixed-order sum
#pragma unroll
    for (int off = 32; off >= 1; off >>= 1) contrib += __shfl_xor(contrib, off);
    __syncthreads();
    float* red = reinterpret_cast<float*>(parent);
    if ((tid & 63) == 0) red[tid >> 6] = contrib;   // 16 wave slots
    __syncthreads();
    if (tid == 0) {
        float s = 0.f;
#pragma unroll
        for (int w = 0; w < 16; ++w) s += red[w];
        partial[blk] = s;
    }
}

__global__ void final_add(const float* __restrict__ partial, float* __restrict__ out) {
    out[0] = partial[0] + partial[1];
}

} // namespace

extern "C" void kernel_launch(void* const* d_in, const int* in_sizes, int n_in,
                              void* d_out, int out_size, void* d_ws, size_t ws_size,
                              hipStream_t stream) {
    const float* d1 = (const float*)d_in[0];
    const float* d2 = (const float*)d_in[1];
    float* out = (float*)d_out;
    float* ws = (float*)d_ws;

    boruvka_loss<<<2, 1024, 0, stream>>>(d1, d2, ws); // writes ws[0], ws[1]
    final_add<<<1, 1, 0, stream>>>(ws, out);
}